// Round 4
// baseline (59.887 us; speedup 1.0000x reference)
//
#include <hip/hip_runtime.h>
#include <hip/hip_bf16.h>
#include <math.h>

#define T_DIM 32
#define B_DIM 128
#define D_DIM 512
#define M_DIM 1024

constexpr float DT = 0.1875f;            // 3.0 / 16

typedef __attribute__((ext_vector_type(8))) short bf16x8;   // 8 bf16 = 4 VGPR
typedef __attribute__((ext_vector_type(4))) float f32x4;    // MFMA acc
typedef __attribute__((ext_vector_type(2))) float f32x2;    // packed (cos,sin)

__device__ __forceinline__ ushort f2bf(float f) {           // RNE fp32->bf16
    unsigned u = __float_as_uint(f);
    u += 0x7FFFu + ((u >> 16) & 1u);
    return (ushort)(u >> 16);
}

// v_sin_f32/v_cos_f32 take input in REVOLUTIONS (ISA: D=sin(S0*2pi)); reduce with floor.
__device__ __forceinline__ void fast_sincos(float theta, float& s, float& c) {
    constexpr float INV_2PI = 0.15915494309189535f;
    float r = theta * INV_2PI;
    r -= floorf(r);
    s = __builtin_amdgcn_sinf(r);
    c = __builtin_amdgcn_cosf(r);
}

// ---------- K1: column inverse norms of A (1024 cols) ----------
__global__ __launch_bounds__(256) void colnorm_kernel(const float* __restrict__ A,
                                                      float* __restrict__ invn) {
    __shared__ float red[256];
    const int mB = blockIdx.x * 16;            // 64 blocks
    const int mo = threadIdx.x & 15;
    const int dg = threadIdx.x >> 4;           // 16 d-groups of 32
    float ss = 0.0f;
#pragma unroll 4
    for (int i = 0; i < 32; ++i) {
        float v = A[(size_t)(dg * 32 + i) * M_DIM + mB + mo];
        ss = fmaf(v, v, ss);
    }
    red[threadIdx.x] = ss;
    __syncthreads();
    for (int s = 128; s >= 16; s >>= 1) {
        if (threadIdx.x < s) red[threadIdx.x] += red[threadIdx.x + s];
        __syncthreads();
    }
    if (threadIdx.x < 16)
        invn[mB + mo] = 1.0f / fmaxf(sqrtf(red[threadIdx.x]), 1e-12f);
}

// ---------- K2: z fp32 -> bf16 (same layout) ----------
__global__ __launch_bounds__(256) void zconv_kernel(const float* __restrict__ z,
                                                    ushort* __restrict__ zb) {
    const size_t i = ((size_t)blockIdx.x * 256 + threadIdx.x) * 8;   // 1024 blocks, exact
    const float4 a = *reinterpret_cast<const float4*>(&z[i]);
    const float4 b = *reinterpret_cast<const float4*>(&z[i + 4]);
    uint4 p;
    p.x = (unsigned)f2bf(a.x) | ((unsigned)f2bf(a.y) << 16);
    p.y = (unsigned)f2bf(a.z) | ((unsigned)f2bf(a.w) << 16);
    p.z = (unsigned)f2bf(b.x) | ((unsigned)f2bf(b.y) << 16);
    p.w = (unsigned)f2bf(b.z) | ((unsigned)f2bf(b.w) << 16);
    *reinterpret_cast<uint4*>(&zb[i]) = p;
}

// ---------- K3: Ant[m][d] = A[d][m] * invn[m], bf16 (LDS tile transpose) ----------
__global__ __launch_bounds__(256) void atrans_kernel(const float* __restrict__ A,
                                                     const float* __restrict__ invn,
                                                     ushort* __restrict__ ant) {
    __shared__ float tile[64][65];
    const int dB = blockIdx.x * 64;            // 8
    const int mB = blockIdx.y * 64;            // 16
#pragma unroll
    for (int it = 0; it < 4; ++it) {
        const int r = it * 16 + (threadIdx.x >> 4);
        const int c = (threadIdx.x & 15) * 4;
        const float4 v = *reinterpret_cast<const float4*>(&A[(size_t)(dB + r) * M_DIM + mB + c]);
        tile[r][c] = v.x; tile[r][c + 1] = v.y; tile[r][c + 2] = v.z; tile[r][c + 3] = v.w;
    }
    __syncthreads();
#pragma unroll
    for (int it = 0; it < 2; ++it) {
        const int ci = it * 256 + threadIdx.x;
        const int orow = ci >> 3;              // 0..63 (m-local)
        const int oc = (ci & 7) * 8;           // 0..56 (d-local)
        const float sc = invn[mB + orow];
        uint4 p;
        p.x = (unsigned)f2bf(tile[oc + 0][orow] * sc) | ((unsigned)f2bf(tile[oc + 1][orow] * sc) << 16);
        p.y = (unsigned)f2bf(tile[oc + 2][orow] * sc) | ((unsigned)f2bf(tile[oc + 3][orow] * sc) << 16);
        p.z = (unsigned)f2bf(tile[oc + 4][orow] * sc) | ((unsigned)f2bf(tile[oc + 5][orow] * sc) << 16);
        p.w = (unsigned)f2bf(tile[oc + 6][orow] * sc) | ((unsigned)f2bf(tile[oc + 7][orow] * sc) << 16);
        *reinterpret_cast<uint4*>(&ant[(size_t)(mB + orow) * D_DIM + dB + oc]) = p;
    }
}

// ---------- K4: fused bf16-MFMA GEMM + CF statistic ----------
// block: 256 thr (4 waves, 2 row-halves x 2 col-halves), tile 128 b-rows x 32 m-cols.
// K=512, BK=64. Registers kept small (accCS[16] f32x2 = 32 VGPR) to avoid scratch.
__global__ __launch_bounds__(256, 4) void fused_kernel(const ushort* __restrict__ zb,
                                                       const ushort* __restrict__ ant,
                                                       float* __restrict__ partials) {
    __shared__ __align__(16) ushort As[128][72];    // +16B pad per row
    __shared__ __align__(16) ushort Bs[32][72];
    __shared__ float wred[2][16][33];               // [wc][col][k | 16+k], padded row
    __shared__ float bred[2];

    const int tid  = threadIdx.x;
    const int mB   = blockIdx.x * 32;               // 32 m-blocks (consecutive share zb slice)
    const int t    = blockIdx.y;                    // 0..31
    const int wave = tid >> 6;
    const int lane = tid & 63;
    const int wr   = wave >> 1;                     // b-row half (0: rows 0-63, 1: 64-127)
    const int wc   = wave & 1;                      // m-col half (0: cols 0-15, 1: 16-31)
    const int l15  = lane & 15;
    const int lhi  = lane >> 4;

    const ushort* zrow = zb + (size_t)t * B_DIM * D_DIM;

    const int ar0 = tid >> 3;            // A rows: tid/8 + 32*q, q=0..3
    const int ac  = (tid & 7) * 8;       // col within BK
    const int br0 = tid >> 3;            // B rows 0..31 (one uint4 each)
    const int bc  = (tid & 7) * 8;

    f32x4 acc[4];
#pragma unroll
    for (int fm = 0; fm < 4; ++fm) acc[fm] = (f32x4)(0.0f);

    uint4 aReg[4], bReg;
#pragma unroll
    for (int q = 0; q < 4; ++q)
        aReg[q] = *reinterpret_cast<const uint4*>(&zrow[(size_t)(ar0 + 32 * q) * D_DIM + ac]);
    bReg = *reinterpret_cast<const uint4*>(&ant[(size_t)(mB + br0) * D_DIM + bc]);

#pragma unroll
    for (int it = 0; it < 8; ++it) {
        __syncthreads();                            // prior MFMA reads done
#pragma unroll
        for (int q = 0; q < 4; ++q)
            *reinterpret_cast<uint4*>(&As[ar0 + 32 * q][ac]) = aReg[q];
        *reinterpret_cast<uint4*>(&Bs[br0][bc]) = bReg;
        __syncthreads();

        if (it < 7) {                               // prefetch next K-tile (issue-early)
            const int k0 = (it + 1) * 64;
#pragma unroll
            for (int q = 0; q < 4; ++q)
                aReg[q] = *reinterpret_cast<const uint4*>(&zrow[(size_t)(ar0 + 32 * q) * D_DIM + k0 + ac]);
            bReg = *reinterpret_cast<const uint4*>(&ant[(size_t)(mB + br0) * D_DIM + k0 + bc]);
        }

#pragma unroll
        for (int ks = 0; ks < 2; ++ks) {
            bf16x8 bf = *reinterpret_cast<const bf16x8*>(&Bs[wc * 16 + l15][ks * 32 + lhi * 8]);
#pragma unroll
            for (int fm = 0; fm < 4; ++fm) {
                bf16x8 af = *reinterpret_cast<const bf16x8*>(&As[wr * 64 + fm * 16 + l15][ks * 32 + lhi * 8]);
                acc[fm] = __builtin_amdgcn_mfma_f32_16x16x32_bf16(af, bf, acc[fm], 0, 0, 0);
            }
        }
    }

    // ---- per-lane CF accumulation: col m fixed (wc*16+l15); 16 b-values (fm x r) ----
    f32x2 accCS[16];
#pragma unroll
    for (int k = 0; k < 16; ++k) accCS[k] = (f32x2)(0.0f);

#pragma unroll
    for (int fm = 0; fm < 4; ++fm)
#pragma unroll
        for (int r = 0; r < 4; ++r) {
            float s1, c1;
            fast_sincos(acc[fm][r] * DT, s1, c1);
            const float c2 = 2.0f * c1;
            f32x2 prev = {1.0f, 0.0f};
            f32x2 cur  = {c1, s1};
            accCS[0] += cur;
#pragma unroll
            for (int k = 1; k < 16; ++k) {
                f32x2 nxt = c2 * cur - prev;        // ffp-contract -> v_pk_fma_f32
                prev = cur; cur = nxt;
                accCS[k] += cur;
            }
        }

    // reduce over the wave's 64 b-rows (4 lane-groups)
#pragma unroll
    for (int k = 0; k < 16; ++k) {
        accCS[k][0] += __shfl_xor(accCS[k][0], 16);
        accCS[k][0] += __shfl_xor(accCS[k][0], 32);
        accCS[k][1] += __shfl_xor(accCS[k][1], 16);
        accCS[k][1] += __shfl_xor(accCS[k][1], 32);
    }

    if (wr == 0 && lane < 16) {
#pragma unroll
        for (int k = 0; k < 16; ++k) {
            wred[wc][l15][k]      = accCS[k][0];
            wred[wc][l15][16 + k] = accCS[k][1];
        }
    }
    __syncthreads();

    if (wr == 1) {
        const float invB = 1.0f / 128.0f;
        float s = 0.0f;
#pragma unroll
        for (int kk = 1; kk <= 16; ++kk) {
            const float tk = DT * (float)kk;
            const float g  = __expf(-0.5f * tk * tk);
            const float w  = ((kk == 16) ? DT : 2.0f * DT) * g;
            const float totC = wred[wc][l15][kk - 1]      + accCS[kk - 1][0];
            const float totS = wred[wc][l15][16 + kk - 1] + accCS[kk - 1][1];
            const float cm = fmaf(totC, invB, -g);
            const float sm = totS * invB;
            s = fmaf(w, fmaf(cm, cm, sm * sm), s);
        }
        // butterfly over all 64 lanes: each col counted 4x (lhi copies)
#pragma unroll
        for (int m = 1; m < 64; m <<= 1) s += __shfl_xor(s, m);
        if (lane == 0) bred[wc] = s;
    }
    __syncthreads();
    if (tid == 0)
        partials[blockIdx.y * 32 + blockIdx.x] = (bred[0] + bred[1]) * 0.25f * 128.0f;
}

// ---------- K5: final reduce of 1024 partials ----------
__global__ __launch_bounds__(256) void finalize_kernel(const float* __restrict__ partials,
                                                       float* __restrict__ out) {
    __shared__ float red[256];
    const int tid = threadIdx.x;
    red[tid] = partials[tid] + partials[tid + 256] + partials[tid + 512] + partials[tid + 768];
    __syncthreads();
    for (int s = 128; s > 0; s >>= 1) {
        if (tid < s) red[tid] += red[tid + s];
        __syncthreads();
    }
    if (tid == 0) out[0] = red[0] * (1.0f / (float)(T_DIM * M_DIM));
}

extern "C" void kernel_launch(void* const* d_in, const int* in_sizes, int n_in,
                              void* d_out, int out_size, void* d_ws, size_t ws_size,
                              hipStream_t stream) {
    const float* z = (const float*)d_in[0];   // (32,128,512)
    const float* A = (const float*)d_in[1];   // (512,1024)
    float* out = (float*)d_out;

    float*  invn     = (float*)d_ws;                                    // 4 KB
    float*  partials = invn + 1024;                                     // 4 KB (1024 fl)
    ushort* zb  = (ushort*)((char*)d_ws + 8192);                        // 4 MB
    ushort* ant = (ushort*)((char*)d_ws + 8192 + (size_t)T_DIM * B_DIM * D_DIM * 2); // 1 MB

    colnorm_kernel<<<64, 256, 0, stream>>>(A, invn);
    zconv_kernel<<<1024, 256, 0, stream>>>(z, zb);
    atrans_kernel<<<dim3(8, 16), 256, 0, stream>>>(A, invn, ant);

    fused_kernel<<<dim3(M_DIM / 32, T_DIM), 256, 0, stream>>>(zb, ant, partials);

    finalize_kernel<<<1, 256, 0, stream>>>(partials, out);
}